// Round 4
// baseline (324.358 us; speedup 1.0000x reference)
//
#include <hip/hip_runtime.h>
#include <math.h>

typedef _Float16 half8 __attribute__((ext_vector_type(8)));
typedef float floatx4 __attribute__((ext_vector_type(4)));
typedef float floatx2 __attribute__((ext_vector_type(2)));

#define B_ 8
#define S_ 4096
// scale = 1/sqrt(128) * log2(e): fold into Q so softmax exp is one v_exp_f32
#define SCALE_L2E 0.12751743008389106f
#define MASK_L2E  -14426.950408889634f   // -10000*log2(e): exp2 -> exact 0
#define L2_10K_OVER_128 0.10381025296522975f  // log2(10000)/128

#define PLD 72    // P LDS row stride (halfs) = 144B (16B-aligned, odd*16)
#define OLD 132   // O accum row stride (floats): 4*row mod 32 spreads banks
#define KW  136   // prep K LDS row stride
#define VW  40    // prep V^T LDS row stride

// ---------------- kernel 1: prep ----------------
// grid (128, 8), block 256: 32 seq rows per block.
//  Qh: RoPE(Q)*SCALE_L2E fp16 row-major [b][s][d]
//  Kp: frag-major: chunk(b,s16,c)[lane=quad*16+n][j] = K[s16*16+n][c*32+quad*8+j]
//  Vp: frag-major: chunk(b,kt,c2,nt)[lane][j] = V[kt*64+c2*32+quad*8+j][nt*16+n]
__global__ __launch_bounds__(256) void prep_kernel(const float* __restrict__ qkv,
                                                   _Float16* __restrict__ Qh,
                                                   _Float16* __restrict__ Kp,
                                                   _Float16* __restrict__ Vp) {
    __shared__ __align__(16) _Float16 Kl[32][KW];
    __shared__ __align__(16) _Float16 Vt[128][VW];
    const int tid = threadIdx.x;
    const int b   = blockIdx.y;
    const int s0  = blockIdx.x * 32;

    // RoPE Q (global) + K (LDS): 32 rows x 64 pairs
#pragma unroll
    for (int it = 0; it < 8; ++it) {
        int idx = tid + it * 256;
        int i = idx & 63, sr = idx >> 6, s = s0 + sr;
        const float* base = qkv + ((size_t)(b * S_ + s)) * 384 + 2 * i;
        floatx2 q2 = *(const floatx2*)base;
        floatx2 k2 = *(const floatx2*)(base + 128);
        float inv = exp2f(-(float)(2 * i) * L2_10K_OVER_128);
        float ang = (float)s * inv;
        float sn, cs; sincosf(ang, &sn, &cs);
        size_t oq = ((size_t)(b * S_ + s)) * 128 + 2 * i;
        Qh[oq]     = (_Float16)((q2[0] * cs - q2[1] * sn) * SCALE_L2E);
        Qh[oq + 1] = (_Float16)((q2[0] * sn + q2[1] * cs) * SCALE_L2E);
        Kl[sr][2 * i]     = (_Float16)(k2[0] * cs - k2[1] * sn);
        Kl[sr][2 * i + 1] = (_Float16)(k2[0] * sn + k2[1] * cs);
    }
    // V -> LDS transpose: 32 rows x 32 float4
#pragma unroll
    for (int it = 0; it < 4; ++it) {
        int idx = tid + it * 256;
        int c = idx & 31, sr = idx >> 5;
        floatx4 v = *(const floatx4*)(qkv + ((size_t)(b * S_ + s0 + sr)) * 384 + 256 + c * 4);
#pragma unroll
        for (int j = 0; j < 4; ++j) Vt[c * 4 + j][sr] = (_Float16)v[j];
    }
    __syncthreads();

    // K frag-major out: 2 s16-tiles x 4 c x 64 lanes
#pragma unroll
    for (int it = 0; it < 2; ++it) {
        int jj = tid + it * 256;
        int t = jj >> 8, c = (jj >> 6) & 3, lane = jj & 63;
        int quad = lane >> 4, n = lane & 15;
        half8 val = *(const half8*)&Kl[t * 16 + n][c * 32 + quad * 8];
        int s16 = (s0 >> 4) + t;
        *(half8*)(Kp + (((size_t)(b * 256 + s16) * 4 + c) * 64 + lane) * 8) = val;
    }
    // V frag-major out: this block covers (kt = s0>>6, c2 = (s0>>5)&1)
    {
        int kt = s0 >> 6, c2 = (s0 >> 5) & 1;
#pragma unroll
        for (int it = 0; it < 2; ++it) {
            int jj = tid + it * 256;
            int nt = (jj >> 6) & 7, lane = jj & 63;
            int quad = lane >> 4, n = lane & 15;
            half8 val = *(const half8*)&Vt[nt * 16 + n][quad * 8];
            *(half8*)(Vp + ((((size_t)(b * 64 + kt) * 2 + c2) * 8 + nt) * 64 + lane) * 8) = val;
        }
    }
}

// ---------------- kernel 2: split-K flash attention ----------------
// grid 1024, block 512 (8 waves). Block owns 32 Q rows (2 MFMA M-tiles).
// Wave w processes K-tiles kt = w, w+8, ... (disjoint) -- no-max softmax makes
// partials purely additive: reduce (O,l) via LDS float atomics at the end.
__global__ __launch_bounds__(512, 2) void attn_kernel(const _Float16* __restrict__ Qh,
                                                      const _Float16* __restrict__ Kp,
                                                      const _Float16* __restrict__ Vp,
                                                      float* __restrict__ out) {
    __shared__ float Oacc[32 * OLD];
    __shared__ float Ll[32];
    __shared__ __align__(16) _Float16 Pl[8][2][16 * PLD];

    const int tid  = threadIdx.x;
    const int wid  = tid >> 6;
    const int lane = tid & 63;
    const int quad = lane >> 4;
    const int l16  = lane & 15;
    const int idx  = blockIdx.x;
    const int b    = idx & 7;               // XCD-swizzle: batch b's K/V stay in one L2
    const int qt   = 127 - (idx >> 3);      // longest q-blocks first
    const int qr0  = qt * 32;

    // zero reduction buffers
    for (int i = tid; i < 32 * OLD; i += 512) Oacc[i] = 0.f;
    if (tid < 32) Ll[tid] = 0.f;
    __syncthreads();

    // Q A-frags for both M-tiles
    half8 aq[2][4];
#pragma unroll
    for (int tile = 0; tile < 2; ++tile) {
        const _Float16* Qb = Qh + ((size_t)(b * S_) + qr0 + tile * 16 + l16) * 128;
#pragma unroll
        for (int c = 0; c < 4; ++c) aq[tile][c] = *(const half8*)(Qb + c * 32 + quad * 8);
    }

    floatx4 o[2][8];
#pragma unroll
    for (int tile = 0; tile < 2; ++tile)
#pragma unroll
        for (int i = 0; i < 8; ++i) o[tile][i] = (floatx4){0.f, 0.f, 0.f, 0.f};
    float rsum[2][4] = {{0.f, 0.f, 0.f, 0.f}, {0.f, 0.f, 0.f, 0.f}};

    const _Float16* Kb = Kp + (size_t)b * 524288;
    const _Float16* Vb = Vp + (size_t)b * 524288;
    const int kt_max = qt >> 1;

    for (int kt = wid; kt <= kt_max; kt += 8) {
        // ---- S = Q K^T : K frags loaded once, used by both M-tiles ----
        floatx4 s4[2][4];
#pragma unroll
        for (int t = 0; t < 4; ++t) {
            const _Float16* kp = Kb + ((size_t)((kt * 4 + t) * 4) * 64 + lane) * 8;
            half8 bk[4];
#pragma unroll
            for (int c = 0; c < 4; ++c) bk[c] = *(const half8*)(kp + c * 512);
            floatx4 a0 = (floatx4){0.f, 0.f, 0.f, 0.f};
            floatx4 a1 = (floatx4){0.f, 0.f, 0.f, 0.f};
#pragma unroll
            for (int c = 0; c < 4; ++c) {
                a0 = __builtin_amdgcn_mfma_f32_16x16x32_f16(aq[0][c], bk[c], a0, 0, 0, 0);
                a1 = __builtin_amdgcn_mfma_f32_16x16x32_f16(aq[1][c], bk[c], a1, 0, 0, 0);
            }
            s4[0][t] = a0; s4[1][t] = a1;
        }

        // ---- causal mask: only the diagonal tile (owned by wave kt_max&7) ----
        if (kt == kt_max) {
#pragma unroll
            for (int tile = 0; tile < 2; ++tile)
#pragma unroll
                for (int t = 0; t < 4; ++t)
#pragma unroll
                    for (int r = 0; r < 4; ++r) {
                        int kcol = kt * 64 + t * 16 + l16;
                        int qr   = qr0 + tile * 16 + quad * 4 + r;
                        if (kcol > qr) s4[tile][t][r] += MASK_L2E;
                    }
        }

        // ---- p = exp2(s), lane-local l, P -> wave-private LDS ----
#pragma unroll
        for (int tile = 0; tile < 2; ++tile)
#pragma unroll
            for (int t = 0; t < 4; ++t)
#pragma unroll
                for (int r = 0; r < 4; ++r) {
                    float p = __builtin_amdgcn_exp2f(s4[tile][t][r]);
                    rsum[tile][r] += p;
                    Pl[wid][tile][(quad * 4 + r) * PLD + t * 16 + l16] = (_Float16)p;
                }

        // ---- O += P V : V frags loaded once per c2, used by both M-tiles ----
#pragma unroll
        for (int c2 = 0; c2 < 2; ++c2) {
            half8 vf[8];
#pragma unroll
            for (int nt = 0; nt < 8; ++nt)
                vf[nt] = *(const half8*)(Vb + ((((size_t)(kt * 2 + c2) * 8 + nt) * 64 + lane) * 8));
#pragma unroll
            for (int tile = 0; tile < 2; ++tile) {
                half8 ap = *(const half8*)&Pl[wid][tile][l16 * PLD + c2 * 32 + quad * 8];
#pragma unroll
                for (int nt = 0; nt < 8; ++nt)
                    o[tile][nt] = __builtin_amdgcn_mfma_f32_16x16x32_f16(ap, vf[nt], o[tile][nt], 0, 0, 0);
            }
        }
    }

    // ---- reduce partials across waves (pure addition; no rescale needed) ----
#pragma unroll
    for (int off = 1; off <= 8; off <<= 1)
#pragma unroll
        for (int tile = 0; tile < 2; ++tile)
#pragma unroll
            for (int r = 0; r < 4; ++r)
                rsum[tile][r] += __shfl_xor(rsum[tile][r], off, 64);
    if (l16 == 0) {
#pragma unroll
        for (int tile = 0; tile < 2; ++tile)
#pragma unroll
            for (int r = 0; r < 4; ++r)
                atomicAdd(&Ll[tile * 16 + quad * 4 + r], rsum[tile][r]);
    }
#pragma unroll
    for (int tile = 0; tile < 2; ++tile)
#pragma unroll
        for (int nt = 0; nt < 8; ++nt)
#pragma unroll
            for (int r = 0; r < 4; ++r)
                atomicAdd(&Oacc[(tile * 16 + quad * 4 + r) * OLD + nt * 16 + l16],
                          o[tile][nt][r]);
    __syncthreads();

    // ---- normalize + coalesced store ----
    float* ob = out + ((size_t)(b * S_) + qr0) * 128;
    for (int i = tid; i < 4096; i += 512) {
        int row = i >> 7, col = i & 127;
        ob[i] = Oacc[row * OLD + col] / Ll[row];
    }
}

extern "C" void kernel_launch(void* const* d_in, const int* in_sizes, int n_in,
                              void* d_out, int out_size, void* d_ws, size_t ws_size,
                              hipStream_t stream) {
    const float* qkv = (const float*)d_in[0];
    float* out = (float*)d_out;
    _Float16* Qh = (_Float16*)d_ws;                                        // 8 MB
    _Float16* Kp = (_Float16*)((char*)d_ws + (size_t)8 * 1024 * 1024);     // 8 MB
    _Float16* Vp = (_Float16*)((char*)d_ws + (size_t)16 * 1024 * 1024);    // 8 MB

    prep_kernel<<<dim3(128, B_), dim3(256), 0, stream>>>(qkv, Qh, Kp, Vp);
    attn_kernel<<<dim3(1024), dim3(512), 0, stream>>>(Qh, Kp, Vp, out);
}

// Round 5
// 211.606 us; speedup vs baseline: 1.5328x; 1.5328x over previous
//
#include <hip/hip_runtime.h>
#include <math.h>

typedef _Float16 half8 __attribute__((ext_vector_type(8)));
typedef float floatx4 __attribute__((ext_vector_type(4)));
typedef float floatx2 __attribute__((ext_vector_type(2)));

#define B_ 8
#define S_ 4096
// scale = 1/sqrt(128) * log2(e): folded into Q so softmax exp is one v_exp_f32
#define SCALE_L2E 0.12751743008389106f
#define MASK_L2E  -14426.950408889634f   // -10000*log2(e): exp2 -> exact 0
#define L2_10K_OVER_128 0.10381025296522975f  // log2(10000)/128

#define PLD 72   // P LDS row stride (halfs) = 144B, 16B-aligned
#define KW  136  // prep K LDS row stride (halfs)
#define VW  24   // prep V^T LDS row stride (halfs) = 48B

// ---------------- kernel 1: prep ----------------
// grid (256, 8), block 256: 16 seq rows per block (one s16-tile).
//  Qh: RoPE(Q)*SCALE_L2E fp16 row-major [b][s][d]
//  Kp: frag-major: chunk(b,s16,c)[lane=quad*16+n][j] = K[s16*16+n][c*32+quad*8+j]
//  Vp: frag-major: chunk(b,kt,c2,nt)[lane=quad*16+n][j] = V[kt*64+c2*32+quad*8+j][nt*16+n]
__global__ __launch_bounds__(256) void prep_kernel(const float* __restrict__ qkv,
                                                   _Float16* __restrict__ Qh,
                                                   _Float16* __restrict__ Kp,
                                                   _Float16* __restrict__ Vp) {
    __shared__ __align__(16) _Float16 Kl[16][KW];
    __shared__ __align__(16) _Float16 Vt[128][VW];
    const int tid = threadIdx.x;
    const int b   = blockIdx.y;
    const int s0  = blockIdx.x * 16;

    // RoPE Q (to global) + K (to LDS): 16 rows x 64 pairs, fast HW sincos
#pragma unroll
    for (int it = 0; it < 4; ++it) {
        int idx = tid + it * 256;
        int i = idx & 63, sr = idx >> 6, s = s0 + sr;
        const float* base = qkv + ((size_t)(b * S_ + s)) * 384 + 2 * i;
        floatx2 q2 = *(const floatx2*)base;
        floatx2 k2 = *(const floatx2*)(base + 128);
        float inv = exp2f(-(float)(2 * i) * L2_10K_OVER_128);
        float ang = (float)s * inv;
        float sn, cs;
        __sincosf(ang, &sn, &cs);
        size_t oq = ((size_t)(b * S_ + s)) * 128 + 2 * i;
        Qh[oq]     = (_Float16)((q2[0] * cs - q2[1] * sn) * SCALE_L2E);
        Qh[oq + 1] = (_Float16)((q2[0] * sn + q2[1] * cs) * SCALE_L2E);
        Kl[sr][2 * i]     = (_Float16)(k2[0] * cs - k2[1] * sn);
        Kl[sr][2 * i + 1] = (_Float16)(k2[0] * sn + k2[1] * cs);
    }
    // V -> LDS transpose: 16 rows x 32 float4 chunks
#pragma unroll
    for (int it = 0; it < 2; ++it) {
        int idx = tid + it * 256;
        int c = idx & 31, sr = idx >> 5;
        floatx4 v = *(const floatx4*)(qkv + ((size_t)(b * S_ + s0 + sr)) * 384 + 256 + c * 4);
#pragma unroll
        for (int j = 0; j < 4; ++j) Vt[c * 4 + j][sr] = (_Float16)v[j];
    }
    __syncthreads();

    // K frag-major out: 4 c-chunks x 64 lanes, coalesced 16B stores
    {
        int c = tid >> 6, lane = tid & 63;
        int quad = lane >> 4, n = lane & 15;
        half8 val = *(const half8*)&Kl[n][c * 32 + quad * 8];
        int s16 = s0 >> 4;
        *(half8*)(Kp + (((size_t)(b * 256 + s16) * 4 + c) * 64 + lane) * 8) = val;
    }
    // V frag-major out: this block covers (kt, c2, quad-pair qp)
    {
        int kt = s0 >> 6, c2 = (s0 >> 5) & 1, qp = (s0 >> 4) & 1;
        int nt = tid >> 5, lq = (tid >> 4) & 1, n = tid & 15;
        int quad = qp * 2 + lq;
        int lane = quad * 16 + n;
        half8 val = *(const half8*)&Vt[nt * 16 + n][lq * 8];
        *(half8*)(Vp + ((((size_t)(b * 64 + kt) * 2 + c2) * 8 + nt) * 64 + lane) * 8) = val;
    }
}

// ---------------- kernel 2: split-K flash attention ----------------
// grid (64, 256), block 64 (1 wave). Unit = (b, qt, chunk of 8 K-tiles).
// No-max softmax => partials are purely additive: fire-and-forget
// global_atomic_add into out (O partials) and Lg (l partials).
__global__ __launch_bounds__(64) void attn_kernel(const _Float16* __restrict__ Qh,
                                                  const _Float16* __restrict__ Kp,
                                                  const _Float16* __restrict__ Vp,
                                                  float* __restrict__ out,
                                                  float* __restrict__ Lg) {
    __shared__ __align__(16) _Float16 Pl[2][16 * PLD];

    const int lane  = threadIdx.x;
    const int quad  = lane >> 4;
    const int l16   = lane & 15;
    const int b     = blockIdx.x & 7;
    const int chunk = blockIdx.x >> 3;
    const int qt    = 255 - blockIdx.y;    // big-qt units first
    const int qr0   = qt * 16;
    const int kt_max = qt >> 2;
    const int c0    = chunk * 8;
    if (c0 > kt_max) return;               // empty unit
    const int kend  = min(kt_max, c0 + 7);

    const _Float16* Qb = Qh + ((size_t)(b * S_) + qr0 + l16) * 128;
    half8 aq[4];
#pragma unroll
    for (int c = 0; c < 4; ++c) aq[c] = *(const half8*)(Qb + c * 32 + quad * 8);

    floatx4 o[8];
#pragma unroll
    for (int i = 0; i < 8; ++i) o[i] = (floatx4){0.f, 0.f, 0.f, 0.f};
    float rsum[4] = {0.f, 0.f, 0.f, 0.f};

    const _Float16* Kb = Kp + (size_t)b * 524288;
    const _Float16* Vb = Vp + (size_t)b * 524288;

    for (int kt = c0; kt <= kend; ++kt) {
        // V frags preload (issue early; consumed after exp)
        half8 vf[2][8];
#pragma unroll
        for (int c2 = 0; c2 < 2; ++c2)
#pragma unroll
            for (int nt = 0; nt < 8; ++nt)
                vf[c2][nt] = *(const half8*)(Vb + (((size_t)(kt * 2 + c2) * 8 + nt) * 64 + lane) * 8);

        // S' = Q K^T (pre-scaled)
        floatx4 s4[4];
#pragma unroll
        for (int t = 0; t < 4; ++t) {
            const _Float16* kp = Kb + ((size_t)((kt * 4 + t) * 4) * 64 + lane) * 8;
            floatx4 acc = (floatx4){0.f, 0.f, 0.f, 0.f};
#pragma unroll
            for (int c = 0; c < 4; ++c) {
                half8 bk = *(const half8*)(kp + c * 512);
                acc = __builtin_amdgcn_mfma_f32_16x16x32_f16(aq[c], bk, acc, 0, 0, 0);
            }
            s4[t] = acc;
        }

        // causal mask: only the diagonal K-tile (last chunk only)
        if (kt == kt_max) {
#pragma unroll
            for (int t = 0; t < 4; ++t)
#pragma unroll
                for (int r = 0; r < 4; ++r) {
                    int kcol = kt * 64 + t * 16 + l16;
                    int qr   = qr0 + quad * 4 + r;
                    if (kcol > qr) s4[t][r] += MASK_L2E;
                }
        }

        // p = exp2(s'), lane-local l, P -> wave-private LDS (C->A transform)
        const int buf = kt & 1;
#pragma unroll
        for (int t = 0; t < 4; ++t)
#pragma unroll
            for (int r = 0; r < 4; ++r) {
                float p = __builtin_amdgcn_exp2f(s4[t][r]);  // masked: exactly 0
                rsum[r] += p;
                Pl[buf][(quad * 4 + r) * PLD + t * 16 + l16] = (_Float16)p;
            }

        // O += P V
#pragma unroll
        for (int c2 = 0; c2 < 2; ++c2) {
            half8 ap = *(const half8*)&Pl[buf][l16 * PLD + c2 * 32 + quad * 8];
#pragma unroll
            for (int nt = 0; nt < 8; ++nt)
                o[nt] = __builtin_amdgcn_mfma_f32_16x16x32_f16(ap, vf[c2][nt], o[nt], 0, 0, 0);
        }
    }

    // l partials: reduce over l16 within quad, one atomic per row
#pragma unroll
    for (int off = 1; off <= 8; off <<= 1)
#pragma unroll
        for (int r = 0; r < 4; ++r)
            rsum[r] += __shfl_xor(rsum[r], off, 64);
    if (l16 == 0) {
#pragma unroll
        for (int r = 0; r < 4; ++r)
            atomicAdd(&Lg[(size_t)(b * S_) + qr0 + quad * 4 + r], rsum[r]);
    }

    // O partials: fire-and-forget global fp32 atomics (no return -> no stall)
    float* ob = out + ((size_t)(b * S_) + qr0) * 128;
#pragma unroll
    for (int nt = 0; nt < 8; ++nt)
#pragma unroll
        for (int r = 0; r < 4; ++r)
            atomicAdd(&ob[(quad * 4 + r) * 128 + nt * 16 + l16], o[nt][r]);
}

// ---------------- kernel 3: normalize ----------------
// out[row][:] /= Lg[row], vectorized float4. 1M float4 over 4096 blocks.
__global__ __launch_bounds__(256) void norm_kernel(float* __restrict__ out,
                                                   const float* __restrict__ Lg) {
    int i = blockIdx.x * 256 + threadIdx.x;      // float4 index
    int row = i >> 5;
    floatx4 v = *(floatx4*)(out + (size_t)i * 4);
    float inv = 1.0f / Lg[row];
    v[0] *= inv; v[1] *= inv; v[2] *= inv; v[3] *= inv;
    *(floatx4*)(out + (size_t)i * 4) = v;
}

extern "C" void kernel_launch(void* const* d_in, const int* in_sizes, int n_in,
                              void* d_out, int out_size, void* d_ws, size_t ws_size,
                              hipStream_t stream) {
    const float* qkv = (const float*)d_in[0];
    float* out = (float*)d_out;
    _Float16* Qh = (_Float16*)d_ws;                                        // 8 MB
    _Float16* Kp = (_Float16*)((char*)d_ws + (size_t)8 * 1024 * 1024);     // 8 MB
    _Float16* Vp = (_Float16*)((char*)d_ws + (size_t)16 * 1024 * 1024);    // 8 MB
    float*    Lg = (float*)((char*)d_ws + (size_t)24 * 1024 * 1024);       // 128 KB

    hipMemsetAsync(out, 0, (size_t)B_ * S_ * 128 * sizeof(float), stream);
    hipMemsetAsync(Lg, 0, (size_t)B_ * S_ * sizeof(float), stream);
    prep_kernel<<<dim3(256, B_), dim3(256), 0, stream>>>(qkv, Qh, Kp, Vp);
    attn_kernel<<<dim3(64, 256), dim3(64), 0, stream>>>(Qh, Kp, Vp, out, Lg);
    norm_kernel<<<dim3(4096), dim3(256), 0, stream>>>(out, Lg);
}

// Round 6
// 167.868 us; speedup vs baseline: 1.9322x; 1.2606x over previous
//
#include <hip/hip_runtime.h>
#include <math.h>

typedef _Float16 half8 __attribute__((ext_vector_type(8)));
typedef float floatx4 __attribute__((ext_vector_type(4)));
typedef float floatx2 __attribute__((ext_vector_type(2)));

#define B_ 8
#define S_ 4096
// scale = 1/sqrt(128) * log2(e): folded into Q so softmax exp is one v_exp_f32
#define SCALE_L2E 0.12751743008389106f
#define MASK_L2E  -14426.950408889634f   // -10000*log2(e): exp2 -> exact 0
#define L2_10K_OVER_128 0.10381025296522975f  // log2(10000)/128

#define PLD 72    // P LDS row stride (halfs) = 144B, 16B-aligned
#define KW  136   // prep K LDS row stride (halfs)
#define VW  24    // prep V^T LDS row stride (halfs)
#define OSTLD 136 // O-staging LDS row stride (halfs)
#define SLOTS_PER_B 576   // sum over qt32 of ceil(tiles/8)

// units before q-block qt32 (chunks = floor(qt32/16)+1)
__device__ __forceinline__ int chunk_prefix(int qt32) {
    int g = qt32 >> 4;
    return qt32 + 8 * g * (g - 1) + (qt32 - (g << 4)) * g;
}

// ---------------- kernel 1: prep (unchanged layouts) ----------------
// grid (256, 8), block 256: 16 seq rows per block.
//  Qh: RoPE(Q)*SCALE_L2E fp16 row-major [b][s][d]
//  Kp: frag-major: chunk(b,s16,c)[lane=quad*16+n][j] = K[s16*16+n][c*32+quad*8+j]
//  Vp: frag-major: chunk(b,kt,c2,nt)[lane=quad*16+n][j] = V[kt*64+c2*32+quad*8+j][nt*16+n]
__global__ __launch_bounds__(256) void prep_kernel(const float* __restrict__ qkv,
                                                   _Float16* __restrict__ Qh,
                                                   _Float16* __restrict__ Kp,
                                                   _Float16* __restrict__ Vp) {
    __shared__ __align__(16) _Float16 Kl[16][KW];
    __shared__ __align__(16) _Float16 Vt[128][VW];
    const int tid = threadIdx.x;
    const int b   = blockIdx.y;
    const int s0  = blockIdx.x * 16;

#pragma unroll
    for (int it = 0; it < 4; ++it) {
        int idx = tid + it * 256;
        int i = idx & 63, sr = idx >> 6, s = s0 + sr;
        const float* base = qkv + ((size_t)(b * S_ + s)) * 384 + 2 * i;
        floatx2 q2 = *(const floatx2*)base;
        floatx2 k2 = *(const floatx2*)(base + 128);
        float inv = exp2f(-(float)(2 * i) * L2_10K_OVER_128);
        float ang = (float)s * inv;
        float sn, cs;
        __sincosf(ang, &sn, &cs);
        size_t oq = ((size_t)(b * S_ + s)) * 128 + 2 * i;
        Qh[oq]     = (_Float16)((q2[0] * cs - q2[1] * sn) * SCALE_L2E);
        Qh[oq + 1] = (_Float16)((q2[0] * sn + q2[1] * cs) * SCALE_L2E);
        Kl[sr][2 * i]     = (_Float16)(k2[0] * cs - k2[1] * sn);
        Kl[sr][2 * i + 1] = (_Float16)(k2[0] * sn + k2[1] * cs);
    }
#pragma unroll
    for (int it = 0; it < 2; ++it) {
        int idx = tid + it * 256;
        int c = idx & 31, sr = idx >> 5;
        floatx4 v = *(const floatx4*)(qkv + ((size_t)(b * S_ + s0 + sr)) * 384 + 256 + c * 4);
#pragma unroll
        for (int j = 0; j < 4; ++j) Vt[c * 4 + j][sr] = (_Float16)v[j];
    }
    __syncthreads();

    {   // K frag-major out
        int c = tid >> 6, lane = tid & 63;
        int quad = lane >> 4, n = lane & 15;
        half8 val = *(const half8*)&Kl[n][c * 32 + quad * 8];
        int s16 = s0 >> 4;
        *(half8*)(Kp + (((size_t)(b * 256 + s16) * 4 + c) * 64 + lane) * 8) = val;
    }
    {   // V frag-major out
        int kt = s0 >> 6, c2 = (s0 >> 5) & 1, qp = (s0 >> 4) & 1;
        int nt = tid >> 5, lq = (tid >> 4) & 1, n = tid & 15;
        int quad = qp * 2 + lq;
        int lane = quad * 16 + n;
        half8 val = *(const half8*)&Vt[nt * 16 + n][lq * 8];
        *(half8*)(Vp + ((((size_t)(b * 64 + kt) * 2 + c2) * 8 + nt) * 64 + lane) * 8) = val;
    }
}

// ---------------- kernel 2a: split-K flash, PARTIAL-STORE path ----------------
// grid (64,128), block 64 (1 wave). Unit = (b, 32-row q-block, chunk of 8 K-tiles).
// Writes fp16 O-partial + f32 l-partial to a private slot. No atomics.
__global__ __launch_bounds__(64) void attn_part_kernel(const _Float16* __restrict__ Qh,
                                                       const _Float16* __restrict__ Kp,
                                                       const _Float16* __restrict__ Vp,
                                                       _Float16* __restrict__ Ppart,
                                                       float* __restrict__ Lpart) {
    __shared__ __align__(16) _Float16 SH[4 * 16 * PLD];  // Pl[tile][buf] in loop; O-staging after

    const int lane  = threadIdx.x;
    const int quad  = lane >> 4;
    const int l16   = lane & 15;
    const int b     = blockIdx.x & 7;
    const int chunk = blockIdx.x >> 3;
    const int qt32  = 127 - blockIdx.y;     // big q-blocks first
    const int qr0   = qt32 * 32;
    const int kt_max = (qr0 + 31) >> 6;
    const int c0    = chunk * 8;
    if (c0 > kt_max) return;
    const int kend  = min(kt_max, c0 + 7);
    const int slot  = b * SLOTS_PER_B + chunk_prefix(qt32) + chunk;

    half8 aq[2][4];
#pragma unroll
    for (int tile = 0; tile < 2; ++tile) {
        const _Float16* Qb = Qh + ((size_t)(b * S_) + qr0 + tile * 16 + l16) * 128;
#pragma unroll
        for (int c = 0; c < 4; ++c) aq[tile][c] = *(const half8*)(Qb + c * 32 + quad * 8);
    }

    floatx4 o[2][8];
#pragma unroll
    for (int tile = 0; tile < 2; ++tile)
#pragma unroll
        for (int i = 0; i < 8; ++i) o[tile][i] = (floatx4){0.f, 0.f, 0.f, 0.f};
    float rsum[2][4] = {{0.f, 0.f, 0.f, 0.f}, {0.f, 0.f, 0.f, 0.f}};

    const _Float16* Kb = Kp + (size_t)b * 524288;
    const _Float16* Vb = Vp + (size_t)b * 524288;

    for (int kt = c0; kt <= kend; ++kt) {
        // S = Q K^T : K frags loaded once, shared by both M-tiles
        floatx4 s4[2][4];
#pragma unroll
        for (int t = 0; t < 4; ++t) {
            const _Float16* kp = Kb + (((size_t)(kt * 16 + t * 4)) * 64 + lane) * 8;
            half8 bk[4];
#pragma unroll
            for (int c = 0; c < 4; ++c) bk[c] = *(const half8*)(kp + c * 512);
            floatx4 a0 = (floatx4){0.f, 0.f, 0.f, 0.f};
            floatx4 a1 = (floatx4){0.f, 0.f, 0.f, 0.f};
#pragma unroll
            for (int c = 0; c < 4; ++c) {
                a0 = __builtin_amdgcn_mfma_f32_16x16x32_f16(aq[0][c], bk[c], a0, 0, 0, 0);
                a1 = __builtin_amdgcn_mfma_f32_16x16x32_f16(aq[1][c], bk[c], a1, 0, 0, 0);
            }
            s4[0][t] = a0; s4[1][t] = a1;
        }

        if (kt == kt_max) {  // causal mask, diagonal tile only
#pragma unroll
            for (int tile = 0; tile < 2; ++tile)
#pragma unroll
                for (int t = 0; t < 4; ++t)
#pragma unroll
                    for (int r = 0; r < 4; ++r) {
                        int kcol = kt * 64 + t * 16 + l16;
                        int qr   = qr0 + tile * 16 + quad * 4 + r;
                        if (kcol > qr) s4[tile][t][r] += MASK_L2E;
                    }
        }

        // p = exp2(s), lane-local l, P -> LDS (C->A layout transform)
        const int buf = kt & 1;
#pragma unroll
        for (int tile = 0; tile < 2; ++tile)
#pragma unroll
            for (int t = 0; t < 4; ++t)
#pragma unroll
                for (int r = 0; r < 4; ++r) {
                    float p = __builtin_amdgcn_exp2f(s4[tile][t][r]);
                    rsum[tile][r] += p;
                    SH[(tile * 2 + buf) * (16 * PLD) + (quad * 4 + r) * PLD + t * 16 + l16] = (_Float16)p;
                }

        // O += P V : V frags loaded once per c2, shared by both M-tiles
#pragma unroll
        for (int c2 = 0; c2 < 2; ++c2) {
            half8 vf[8];
#pragma unroll
            for (int nt = 0; nt < 8; ++nt)
                vf[nt] = *(const half8*)(Vb + (((size_t)(kt * 2 + c2) * 8 + nt) * 64 + lane) * 8);
#pragma unroll
            for (int tile = 0; tile < 2; ++tile) {
                half8 ap = *(const half8*)&SH[(tile * 2 + buf) * (16 * PLD) + l16 * PLD + c2 * 32 + quad * 8];
#pragma unroll
                for (int nt = 0; nt < 8; ++nt)
                    o[tile][nt] = __builtin_amdgcn_mfma_f32_16x16x32_f16(ap, vf[nt], o[tile][nt], 0, 0, 0);
            }
        }
    }

    // l partials: reduce over l16, plain store (no atomics)
#pragma unroll
    for (int off = 1; off <= 8; off <<= 1)
#pragma unroll
        for (int tile = 0; tile < 2; ++tile)
#pragma unroll
            for (int r = 0; r < 4; ++r)
                rsum[tile][r] += __shfl_xor(rsum[tile][r], off, 64);
    if (l16 == 0) {
#pragma unroll
        for (int tile = 0; tile < 2; ++tile)
#pragma unroll
            for (int r = 0; r < 4; ++r)
                Lpart[(size_t)slot * 32 + tile * 16 + quad * 4 + r] = rsum[tile][r];
    }

    // O partial: C-layout -> LDS fp16 staging -> coalesced 16B streaming stores
    _Float16* Ost = SH;   // 32 x OSTLD = 4352 halfs <= 4608 (reuse, same wave)
#pragma unroll
    for (int tile = 0; tile < 2; ++tile)
#pragma unroll
        for (int nt = 0; nt < 8; ++nt)
#pragma unroll
            for (int r = 0; r < 4; ++r)
                Ost[(tile * 16 + quad * 4 + r) * OSTLD + nt * 16 + l16] = (_Float16)o[tile][nt][r];
    _Float16* pp = Ppart + (size_t)slot * 4096;
#pragma unroll
    for (int i = 0; i < 8; ++i) {
        int idx = lane + i * 64;            // half8-group: row=idx>>4, colgrp=idx&15
        half8 v = *(const half8*)&Ost[(idx >> 4) * OSTLD + (idx & 15) * 8];
        *(half8*)(pp + (size_t)idx * 8) = v;
    }
}

// ---------------- kernel 2b: reduce partials + normalize ----------------
// grid 1024 (= B x 128 q-blocks), block 256. Sums <=8 fp16 partials, divides by l.
__global__ __launch_bounds__(256) void reduce_kernel(const _Float16* __restrict__ Ppart,
                                                     const float* __restrict__ Lpart,
                                                     float* __restrict__ out) {
    const int bid  = blockIdx.x;
    const int b    = bid >> 7;
    const int qt32 = bid & 127;
    const int qr0  = qt32 * 32;
    const int nch  = (((qr0 + 31) >> 6) >> 3) + 1;
    const int slot0 = b * SLOTS_PER_B + chunk_prefix(qt32);
    const _Float16* pp = Ppart + (size_t)slot0 * 4096;
    const float* lp = Lpart + (size_t)slot0 * 32;
    const int tid = threadIdx.x;

#pragma unroll
    for (int j = 0; j < 2; ++j) {
        int idx = tid + j * 256;            // half8 group 0..511
        int row = idx >> 4;
        float acc[8] = {0.f, 0.f, 0.f, 0.f, 0.f, 0.f, 0.f, 0.f};
        float l = 0.f;
        for (int c = 0; c < nch; ++c) {
            half8 v = *(const half8*)(pp + (size_t)c * 4096 + (size_t)idx * 8);
#pragma unroll
            for (int k = 0; k < 8; ++k) acc[k] += (float)v[k];
            l += lp[c * 32 + row];
        }
        float inv = 1.0f / l;
        float* ob = out + ((size_t)(b * S_) + qr0) * 128 + (size_t)idx * 8;
        floatx4 o0 = (floatx4){acc[0] * inv, acc[1] * inv, acc[2] * inv, acc[3] * inv};
        floatx4 o1 = (floatx4){acc[4] * inv, acc[5] * inv, acc[6] * inv, acc[7] * inv};
        *(floatx4*)ob = o0;
        *(floatx4*)(ob + 4) = o1;
    }
}

// ---------------- fallback (ws too small): R5 atomic path ----------------
__global__ __launch_bounds__(64) void attn_atomic_kernel(const _Float16* __restrict__ Qh,
                                                         const _Float16* __restrict__ Kp,
                                                         const _Float16* __restrict__ Vp,
                                                         float* __restrict__ out,
                                                         float* __restrict__ Lg) {
    __shared__ __align__(16) _Float16 Pl[2][16 * PLD];
    const int lane = threadIdx.x, quad = lane >> 4, l16 = lane & 15;
    const int b = blockIdx.x & 7, chunk = blockIdx.x >> 3;
    const int qt = 255 - blockIdx.y, qr0 = qt * 16;
    const int kt_max = qt >> 2, c0 = chunk * 8;
    if (c0 > kt_max) return;
    const int kend = min(kt_max, c0 + 7);
    const _Float16* Qb = Qh + ((size_t)(b * S_) + qr0 + l16) * 128;
    half8 aq[4];
#pragma unroll
    for (int c = 0; c < 4; ++c) aq[c] = *(const half8*)(Qb + c * 32 + quad * 8);
    floatx4 o[8];
#pragma unroll
    for (int i = 0; i < 8; ++i) o[i] = (floatx4){0.f, 0.f, 0.f, 0.f};
    float rsum[4] = {0.f, 0.f, 0.f, 0.f};
    const _Float16* Kb = Kp + (size_t)b * 524288;
    const _Float16* Vb = Vp + (size_t)b * 524288;
    for (int kt = c0; kt <= kend; ++kt) {
        half8 vf[2][8];
#pragma unroll
        for (int c2 = 0; c2 < 2; ++c2)
#pragma unroll
            for (int nt = 0; nt < 8; ++nt)
                vf[c2][nt] = *(const half8*)(Vb + (((size_t)(kt * 2 + c2) * 8 + nt) * 64 + lane) * 8);
        floatx4 s4[4];
#pragma unroll
        for (int t = 0; t < 4; ++t) {
            const _Float16* kp = Kb + ((size_t)((kt * 4 + t) * 4) * 64 + lane) * 8;
            floatx4 acc = (floatx4){0.f, 0.f, 0.f, 0.f};
#pragma unroll
            for (int c = 0; c < 4; ++c) {
                half8 bk = *(const half8*)(kp + c * 512);
                acc = __builtin_amdgcn_mfma_f32_16x16x32_f16(aq[c], bk, acc, 0, 0, 0);
            }
            s4[t] = acc;
        }
        if (kt == kt_max) {
#pragma unroll
            for (int t = 0; t < 4; ++t)
#pragma unroll
                for (int r = 0; r < 4; ++r) {
                    int kcol = kt * 64 + t * 16 + l16;
                    int qr = qr0 + quad * 4 + r;
                    if (kcol > qr) s4[t][r] += MASK_L2E;
                }
        }
        const int buf = kt & 1;
#pragma unroll
        for (int t = 0; t < 4; ++t)
#pragma unroll
            for (int r = 0; r < 4; ++r) {
                float p = __builtin_amdgcn_exp2f(s4[t][r]);
                rsum[r] += p;
                Pl[buf][(quad * 4 + r) * PLD + t * 16 + l16] = (_Float16)p;
            }
#pragma unroll
        for (int c2 = 0; c2 < 2; ++c2) {
            half8 ap = *(const half8*)&Pl[buf][l16 * PLD + c2 * 32 + quad * 8];
#pragma unroll
            for (int nt = 0; nt < 8; ++nt)
                o[nt] = __builtin_amdgcn_mfma_f32_16x16x32_f16(ap, vf[c2][nt], o[nt], 0, 0, 0);
        }
    }
#pragma unroll
    for (int off = 1; off <= 8; off <<= 1)
#pragma unroll
        for (int r = 0; r < 4; ++r)
            rsum[r] += __shfl_xor(rsum[r], off, 64);
    if (l16 == 0) {
#pragma unroll
        for (int r = 0; r < 4; ++r)
            atomicAdd(&Lg[(size_t)(b * S_) + qr0 + quad * 4 + r], rsum[r]);
    }
    float* ob = out + ((size_t)(b * S_) + qr0) * 128;
#pragma unroll
    for (int nt = 0; nt < 8; ++nt)
#pragma unroll
        for (int r = 0; r < 4; ++r)
            atomicAdd(&ob[(quad * 4 + r) * 128 + nt * 16 + l16], o[nt][r]);
}

__global__ __launch_bounds__(256) void norm_kernel(float* __restrict__ out,
                                                   const float* __restrict__ Lg) {
    int i = blockIdx.x * 256 + threadIdx.x;
    int row = i >> 5;
    floatx4 v = *(floatx4*)(out + (size_t)i * 4);
    float inv = 1.0f / Lg[row];
    v[0] *= inv; v[1] *= inv; v[2] *= inv; v[3] *= inv;
    *(floatx4*)(out + (size_t)i * 4) = v;
}

extern "C" void kernel_launch(void* const* d_in, const int* in_sizes, int n_in,
                              void* d_out, int out_size, void* d_ws, size_t ws_size,
                              hipStream_t stream) {
    const float* qkv = (const float*)d_in[0];
    float* out = (float*)d_out;
    const size_t MB = 1024 * 1024;
    _Float16* Qh = (_Float16*)d_ws;                          // 8 MB
    _Float16* Kp = (_Float16*)((char*)d_ws + 8 * MB);        // 8 MB
    _Float16* Vp = (_Float16*)((char*)d_ws + 16 * MB);       // 8 MB

    const size_t lpart_bytes = (size_t)B_ * SLOTS_PER_B * 32 * sizeof(float);     // 576 KB
    const size_t ppart_bytes = (size_t)B_ * SLOTS_PER_B * 4096 * sizeof(_Float16); // 36 MB
    const size_t need = 25 * MB + ppart_bytes;

    prep_kernel<<<dim3(256, B_), dim3(256), 0, stream>>>(qkv, Qh, Kp, Vp);

    if (ws_size >= need) {
        float*    Lpart = (float*)((char*)d_ws + 24 * MB);       // 576 KB
        _Float16* Ppart = (_Float16*)((char*)d_ws + 25 * MB);    // 36 MB
        (void)lpart_bytes;
        attn_part_kernel<<<dim3(64, 128), dim3(64), 0, stream>>>(Qh, Kp, Vp, Ppart, Lpart);
        reduce_kernel<<<dim3(1024), dim3(256), 0, stream>>>(Ppart, Lpart, out);
    } else {
        float* Lg = (float*)((char*)d_ws + 24 * MB);             // 128 KB
        hipMemsetAsync(out, 0, (size_t)B_ * S_ * 128 * sizeof(float), stream);
        hipMemsetAsync(Lg, 0, (size_t)B_ * S_ * sizeof(float), stream);
        attn_atomic_kernel<<<dim3(64, 256), dim3(64), 0, stream>>>(Qh, Kp, Vp, out, Lg);
        norm_kernel<<<dim3(4096), dim3(256), 0, stream>>>(out, Lg);
    }
}